// Round 2
// baseline (168.888 us; speedup 1.0000x reference)
//
#include <hip/hip_runtime.h>
#include <hip/hip_bf16.h>
#include <stdint.h>

// Problem constants
#define B_SZ 4
#define T_LEN 8192
#define D_DIM 512
#define M_TOT (B_SZ * T_LEN)  // 32768
#define CHUNK 128             // scan chunk == GEMM M-tile
#define NCH (T_LEN / CHUNK)   // 64 chunks per batch
#define SCPAD 136             // padded stride for the f32 scan tile (bank-spread)

typedef __attribute__((ext_vector_type(8))) short bf16x8v;
typedef __attribute__((ext_vector_type(4))) float f32x4v;

__device__ __forceinline__ unsigned short f2bf(float f) {
  unsigned int u = __float_as_uint(f);
  u += 0x7fffu + ((u >> 16) & 1u);
  return (unsigned short)(u >> 16);
}
__device__ __forceinline__ float bf2f(unsigned short b) {
  return __uint_as_float(((unsigned int)b) << 16);
}
__device__ __forceinline__ float sigmoidf_(float x) { return 1.0f / (1.0f + expf(-x)); }

// ---------------------------------------------------------------------------
// Blocks 0..1023: convert W_B, W_C to bf16. Block 1024: powA[i][ch] = a^(i+1).
__global__ void prep_k(const float* __restrict__ Wb, const float* __restrict__ Wc,
                       const float* __restrict__ A, unsigned short* __restrict__ wbf,
                       float* __restrict__ powA) {
  if (blockIdx.x < 1024) {
    int i = blockIdx.x * 256 + threadIdx.x;
    wbf[i] = f2bf(Wb[i]);
    wbf[262144 + i] = f2bf(Wc[i]);
  } else {
    for (int s = 0; s < 2; ++s) {
      int ch = s * 256 + threadIdx.x;
      float a = sigmoidf_(A[ch]);
      float p = a;
      for (int i = 0; i < CHUNK; ++i) {
        powA[i * D_DIM + ch] = p;
        p *= a;
      }
    }
  }
}

// ---------------------------------------------------------------------------
// In-place chunk-carry prefix: cst[bi][c][ch] holds local-final h on entry,
// carry (state entering chunk c) on exit.  grid=B_SZ, block=512.
__global__ void carry_k(const float* __restrict__ A, float* __restrict__ cst) {
  const int ch = threadIdx.x;
  const int bi = blockIdx.x;
  float a = sigmoidf_(A[ch]);
  float p = a;
#pragma unroll
  for (int i = 0; i < 7; ++i) p *= p;  // a^128
  float H = 0.f;
#pragma unroll 8
  for (int c = 0; c < NCH; ++c) {
    size_t off = ((size_t)bi * NCH + c) * D_DIM + ch;
    float lf = cst[off];
    cst[off] = H;
    H = fmaf(p, H, lf);
  }
}

// ---------------------------------------------------------------------------
// 128x128x(BK=64) bf16 MFMA GEMM vs transposed weights, 2-phase double-buffer.
// MODE 0: A = x (f32, converted during staging); epilogue = in-LDS chunk scan,
//         writes h_local (bf16) + chunk-final state. C unused.
// MODE 1: A = h_local (bf16) with carry fix applied in registers during
//         staging; epilogue = LDS-transposed coalesced f32 C store.
template <int MODE>
__global__ __launch_bounds__(256, 2) void gemm_k(
    const void* __restrict__ Aptr, const unsigned short* __restrict__ Bw,
    float* __restrict__ C, const float* __restrict__ Adecay,
    unsigned short* __restrict__ hOut, float* __restrict__ cst,
    const float* __restrict__ powA) {
  constexpr int K = 512, N = 512;
  __shared__ union {
    unsigned short st[2][2][8192];   // [buf][A/B][128*64] bf16 (64 KB)
    float sc[CHUNK * SCPAD];         // f32 epilogue tile (69.6 KB)
  } sm;

  const int tid = threadIdx.x;
  const int lane = tid & 63;
  const int wave = tid >> 6;
  const int wm = (wave >> 1) * 64;
  const int wn = (wave & 1) * 64;
  const int bm = blockIdx.y * 128;
  const int bn = blockIdx.x * 128;
  const int l15 = lane & 15;
  const int lq16 = (lane >> 4) * 16;
  const int lr4 = (lane >> 4) * 4;
  const int r0 = tid >> 3, u8 = tid & 7;    // bf16 staging coords
  const int r16 = tid >> 4, u16 = tid & 15; // f32 staging coords

  f32x4v acc[4][4] = {};

  // prefetch registers
  float4 a1v[8];
  uint4 a2h[4];
  float4 a2p[4][2];
  float4 a2c[2];
  uint4 bv[4];

  auto loadA = [&](int k0) {
    if constexpr (MODE == 0) {
      const float* Af = (const float*)Aptr;
#pragma unroll
      for (int it = 0; it < 8; ++it) {
        int row = it * 16 + r16;
        a1v[it] = *(const float4*)&Af[(size_t)(bm + row) * K + k0 + u16 * 4];
      }
    } else {
      const unsigned short* Ah = (const unsigned short*)Aptr;
#pragma unroll
      for (int it = 0; it < 4; ++it) {
        int row = it * 32 + r0;
        a2h[it] = *(const uint4*)&Ah[(size_t)(bm + row) * K + k0 + u8 * 8];
        const float* pp = &powA[row * D_DIM + k0 + u8 * 8];
        a2p[it][0] = *(const float4*)pp;
        a2p[it][1] = *(const float4*)(pp + 4);
      }
      const float* cc = &cst[(size_t)blockIdx.y * D_DIM + k0 + u8 * 8];
      a2c[0] = *(const float4*)cc;
      a2c[1] = *(const float4*)(cc + 4);
    }
#pragma unroll
    for (int it = 0; it < 4; ++it) {
      int row = it * 32 + r0;
      bv[it] = *(const uint4*)&Bw[(size_t)(bn + row) * K + k0 + u8 * 8];
    }
  };

  auto writeS = [&](int buf) {
    if constexpr (MODE == 0) {
#pragma unroll
      for (int it = 0; it < 8; ++it) {
        int row = it * 16 + r16;
        float4 v = a1v[it];
        unsigned int lo = (unsigned)f2bf(v.x) | ((unsigned)f2bf(v.y) << 16);
        unsigned int hi = (unsigned)f2bf(v.z) | ((unsigned)f2bf(v.w) << 16);
        int byte = (row * 128 + u16 * 8) ^ ((row & 7) << 4);
        *(uint2*)((char*)sm.st[buf][0] + byte) = make_uint2(lo, hi);
      }
    } else {
#pragma unroll
      for (int it = 0; it < 4; ++it) {
        int row = it * 32 + r0;
        const unsigned int* hw = (const unsigned int*)&a2h[it];
        const float* pf = (const float*)&a2p[it][0];
        const float* cf = (const float*)&a2c[0];
        unsigned int w[4];
#pragma unroll
        for (int q = 0; q < 4; ++q) {
          float g0 = fmaf(pf[2 * q], cf[2 * q], bf2f((unsigned short)(hw[q] & 0xffff)));
          float g1 = fmaf(pf[2 * q + 1], cf[2 * q + 1], bf2f((unsigned short)(hw[q] >> 16)));
          w[q] = (unsigned)f2bf(g0) | ((unsigned)f2bf(g1) << 16);
        }
        int byte = (row * 128 + u8 * 16) ^ ((row & 7) << 4);
        *(uint4*)((char*)sm.st[buf][0] + byte) = make_uint4(w[0], w[1], w[2], w[3]);
      }
    }
#pragma unroll
    for (int it = 0; it < 4; ++it) {
      int row = it * 32 + r0;
      int byte = (row * 128 + u8 * 16) ^ ((row & 7) << 4);
      *(uint4*)((char*)sm.st[buf][1] + byte) = bv[it];
    }
  };

  // prologue
  loadA(0);
  writeS(0);
  __syncthreads();
  int cur = 0;
#pragma unroll 2
  for (int t = 0; t < 8; ++t) {
    if (t < 7) loadA((t + 1) * 64);  // issue next tile's loads under MFMA
#pragma unroll
    for (int ks = 0; ks < 2; ++ks) {
      bf16x8v af[4], bfr[4];
#pragma unroll
      for (int i = 0; i < 4; ++i) {
        int row = wm + i * 16 + l15;
        int byte = (row * 128 + ks * 64 + lq16) ^ ((row & 7) << 4);
        af[i] = *(const bf16x8v*)((const char*)sm.st[cur][0] + byte);
      }
#pragma unroll
      for (int j = 0; j < 4; ++j) {
        int row = wn + j * 16 + l15;
        int byte = (row * 128 + ks * 64 + lq16) ^ ((row & 7) << 4);
        bfr[j] = *(const bf16x8v*)((const char*)sm.st[cur][1] + byte);
      }
#pragma unroll
      for (int i = 0; i < 4; ++i)
#pragma unroll
        for (int j = 0; j < 4; ++j)
          acc[i][j] = __builtin_amdgcn_mfma_f32_16x16x32_bf16(af[i], bfr[j], acc[i][j], 0, 0, 0);
    }
    if (t < 7) {
      writeS(cur ^ 1);  // waits vmcnt for next tile, then LDS write
      __syncthreads();  // one barrier per K-step
      cur ^= 1;
    }
  }
  __syncthreads();  // LDS reuse by epilogue

  if constexpr (MODE == 0) {
    // ---- fused chunk-local scan over the 128 t-rows of this tile ----
#pragma unroll
    for (int i = 0; i < 4; ++i)
#pragma unroll
      for (int j = 0; j < 4; ++j)
#pragma unroll
        for (int r = 0; r < 4; ++r)
          sm.sc[(wm + i * 16 + lr4 + r) * SCPAD + wn + j * 16 + l15] = acc[i][j][r];
    __syncthreads();
    if (tid < 128) {
      float a = sigmoidf_(Adecay[bn + tid]);
      float h = 0.f;
#pragma unroll 8
      for (int t = 0; t < CHUNK; ++t) {
        h = fmaf(a, h, sm.sc[t * SCPAD + tid]);
        sm.sc[t * SCPAD + tid] = h;
      }
      cst[(size_t)blockIdx.y * D_DIM + bn + tid] = h;  // chunk-local final
    }
    __syncthreads();
    // write h_local as bf16, 256B row segments (full lines)
#pragma unroll
    for (int p = 0; p < 8; ++p) {
      int row = p * 16 + (tid >> 4);
      int c8 = (tid & 15) * 8;
      const float* s = &sm.sc[row * SCPAD + c8];
      unsigned int w[4];
#pragma unroll
      for (int q = 0; q < 4; ++q)
        w[q] = (unsigned)f2bf(s[2 * q]) | ((unsigned)f2bf(s[2 * q + 1]) << 16);
      *(uint4*)&hOut[(size_t)(bm + row) * D_DIM + bn + c8] = make_uint4(w[0], w[1], w[2], w[3]);
    }
  } else {
    // ---- coalesced C store via per-wave LDS transpose (stride 68 f32) ----
    float* tp = sm.sc + wave * (16 * 68);
#pragma unroll
    for (int i = 0; i < 4; ++i) {
#pragma unroll
      for (int j = 0; j < 4; ++j)
#pragma unroll
        for (int r = 0; r < 4; ++r)
          tp[(lr4 + r) * 68 + j * 16 + l15] = acc[i][j][r];
#pragma unroll
      for (int p = 0; p < 4; ++p) {
        f32x4v v = *(const f32x4v*)&tp[(p * 4 + (lane >> 4)) * 68 + l15 * 4];
        *(f32x4v*)&C[(size_t)(bm + wm + i * 16 + p * 4 + (lane >> 4)) * N + bn + wn + l15 * 4] = v;
      }
    }
  }
}

// ---------------------------------------------------------------------------
extern "C" void kernel_launch(void* const* d_in, const int* in_sizes, int n_in,
                              void* d_out, int out_size, void* d_ws, size_t ws_size,
                              hipStream_t stream) {
  const float* x = (const float*)d_in[0];
  const float* W_B = (const float*)d_in[1];
  const float* W_C = (const float*)d_in[2];
  const float* A = (const float*)d_in[3];
  float* out = (float*)d_out;
  char* ws = (char*)d_ws;

  // ws: [0,512K) Wb bf16 | [512K,1M) Wc bf16 | [1M,1.25M) powA f32 |
  //     [1.25M,1.75M) chunk-state f32 | [1.75M, +32M) h_local bf16   (~33.75MB)
  unsigned short* Wb = (unsigned short*)ws;
  unsigned short* Wc = Wb + 262144;
  float* powA = (float*)(ws + 0x100000);
  float* cst = (float*)(ws + 0x140000);
  unsigned short* hbf = (unsigned short*)(ws + 0x1C0000);

  prep_k<<<1025, 256, 0, stream>>>(W_B, W_C, A, Wb, powA);

  dim3 gg(D_DIM / 128, M_TOT / 128);  // (4, 256)
  gemm_k<0><<<gg, 256, 0, stream>>>(x, Wb, out, A, hbf, cst, powA);
  carry_k<<<B_SZ, 512, 0, stream>>>(A, cst);
  gemm_k<1><<<gg, 256, 0, stream>>>(hbf, Wc, out, A, nullptr, cst, powA);
}